// Round 1
// 252.437 us; speedup vs baseline: 1.0771x; 1.0771x over previous
//
#include <hip/hip_runtime.h>
#include <stdint.h>

#define NLOC   21824
#define NQUAD  5456          // NLOC/4
#define BATCH  8
#define MAXDET 1000
#define NCLS   80

struct LevelPtrs {
    const float* cls[5];
    const float* cnt[5];
    const float* reg[5];
};

// ---------------------------------------------------------------------------
// K1: per-location score/class/box. Block = 8 class-partitions x 32 quads.
// Argmax over RAW LOGITS (sigmoid strictly monotone); sigmoid once per
// location in the epilogue (bit-identical scores).  [unchanged — verified]
// ---------------------------------------------------------------------------
__global__ __launch_bounds__(256) void k_stage1(LevelPtrs lp, float* scores,
                                                int* cls_out, float4* boxes) {
    __shared__ float4 bl4[8][32];
    __shared__ int4   bc4[8][32];
    int tid = threadIdx.x;
    int p   = tid >> 5;             // class partition (classes p*10..p*10+9)
    int qq  = tid & 31;
    int blk = blockIdx.x;
    int b   = blockIdx.y;

    int lvl, qoff, logw, strd;
    if (blk < 128)      { lvl = 0; qoff = 0;    logw = 7; strd = 8;   }
    else if (blk < 160) { lvl = 1; qoff = 4096; logw = 6; strd = 16;  }
    else if (blk < 168) { lvl = 2; qoff = 5120; logw = 5; strd = 32;  }
    else if (blk < 170) { lvl = 3; qoff = 5376; logw = 4; strd = 64;  }
    else                { lvl = 4; qoff = 5440; logw = 3; strd = 128; }

    int quad  = blk * 32 + qq;
    bool valid = quad < NQUAD;
    int ql   = quad - qoff;
    int loc  = ql * 4;
    int hw   = 1 << (2 * logw);
    int hw4  = hw >> 2;

    float bl[4] = {-3.0e38f, -3.0e38f, -3.0e38f, -3.0e38f};
    int   bc[4] = {0, 0, 0, 0};
    if (valid) {
        const float4* cp = (const float4*)(lp.cls[lvl] + (size_t)(b * NCLS) * hw + loc);
        int c0 = p * 10;
#pragma unroll
        for (int g = 0; g < 2; ++g) {
            float4 lv[5];
#pragma unroll
            for (int k = 0; k < 5; ++k)
                lv[k] = cp[(size_t)(c0 + g * 5 + k) * hw4];
#pragma unroll
            for (int k = 0; k < 5; ++k) {
                int c = c0 + g * 5 + k;
                const float* lf = (const float*)&lv[k];
#pragma unroll
                for (int u = 0; u < 4; ++u)
                    if (lf[u] > bl[u]) { bl[u] = lf[u]; bc[u] = c; }
            }
        }
    }
    bl4[p][qq] = make_float4(bl[0], bl[1], bl[2], bl[3]);
    bc4[p][qq] = make_int4(bc[0], bc[1], bc[2], bc[3]);
    __syncthreads();

    if (tid < 32 && valid) {
        int q = tid;
        float4 B = bl4[0][q]; int4 C = bc4[0][q];
        float bestl[4] = {B.x, B.y, B.z, B.w};
        int   bestc[4] = {C.x, C.y, C.z, C.w};
#pragma unroll
        for (int pp = 1; pp < 8; ++pp) {
            float4 Bp = bl4[pp][q]; int4 Cp = bc4[pp][q];
            const float* bf = (const float*)&Bp;
            const int*   cf = (const int*)&Cp;
#pragma unroll
            for (int u = 0; u < 4; ++u)
                if (bf[u] > bestl[u]) { bestl[u] = bf[u]; bestc[u] = cf[u]; }
        }

        float4 lcv = *(const float4*)(lp.cnt[lvl] + (size_t)b * hw + loc);
        const float* lc = (const float*)&lcv;

        const float4* rp = (const float4*)(lp.reg[lvl] + (size_t)(b * 4) * hw + loc);
        float4 r0v = rp[0], r1v = rp[hw4], r2v = rp[2 * hw4], r3v = rp[3 * hw4];
        const float* r0 = (const float*)&r0v;
        const float* r1 = (const float*)&r1v;
        const float* r2 = (const float*)&r2v;
        const float* r3 = (const float*)&r3v;

        int x = loc & ((1 << logw) - 1);
        int y = loc >> logw;
        float cy = (float)(y * strd + (strd >> 1));

        float sc4[4]; int cl4[4]; float4 bx4[4];
#pragma unroll
        for (int u = 0; u < 4; ++u) {
            float e = expf(-bestl[u]);
            float sig_cls = 1.0f / (1.0f + e);
            float sig_cnt = 1.0f / (1.0f + expf(-lc[u]));
            sc4[u] = sqrtf(__fmul_rn(sig_cls, sig_cnt));
            cl4[u] = bestc[u] + 1;
            float cx = (float)((x + u) * strd + (strd >> 1));
            bx4[u] = make_float4(__fsub_rn(cx, r0[u]), __fsub_rn(cy, r1[u]),
                                 __fadd_rn(cx, r2[u]), __fadd_rn(cy, r3[u]));
        }

        int o = b * NLOC + quad * 4;
        *(float4*)(scores + o) = make_float4(sc4[0], sc4[1], sc4[2], sc4[3]);
        *(int4*)(cls_out + o)  = make_int4(cl4[0], cl4[1], cl4[2], cl4[3]);
#pragma unroll
        for (int u = 0; u < 4; ++u) boxes[o + u] = bx4[u];
    }
}

// ---------------------------------------------------------------------------
// K2 (merged select+prep), latency-optimized:
//  * scores register-cached (ONE global pass instead of five)
//  * 256-bin suffix scan + threshold pick done by wave 0 via shfl
//    (3 barriers/pass instead of ~18)
//  * rank-by-count: second key-half skipped unless cnt>1024; key stream
//    8-unrolled against zero-padded LDS tail
// Semantics identical: exact top-1000 radix select, rank = #keys greater,
// key = (score_bits<<32)|~n  (ties at equal score -> smaller n first).
// ---------------------------------------------------------------------------
__global__ __launch_bounds__(1024) void k_select(const uint32_t* scores_u,
                                                 const float4* boxes,
                                                 const int* cls_ws,
                                                 float* topk_score, float4* gbox,
                                                 int* gcls, float4* obox,
                                                 float* areas, uint64_t* nzmask) {
    __shared__ __align__(16) uint32_t hist[256];
    __shared__ uint64_t keys[2048 + 8];
    __shared__ uint32_t prefix_sh, cnt_sh;
    __shared__ int R_sh;
    __shared__ float redmax[16];
    __shared__ float maxc_sh;

    int b = blockIdx.x, tid = threadIdx.x;
    if (tid < 16) nzmask[b * 16 + tid] = 0;   // consumed by k_iou (later dispatch)
    if (tid == 0) cnt_sh = 0;
    const uint4* sc4 = (const uint4*)(scores_u + (size_t)b * NLOC);

    // ---- register-cache all scores: 6 uint4 per thread (static indexing) ----
    uint4 sv[6];
#pragma unroll
    for (int it = 0; it < 6; ++it) {
        int n4 = tid + it * 1024;
        sv[it] = make_uint4(0u, 0u, 0u, 0u);
        if (n4 < NQUAD) sv[it] = sc4[n4];
    }

    // ---- 4-pass exact radix select (MSB->LSB), all from registers ----
    uint32_t prefix = 0;
    int R = MAXDET;
    for (int d = 3; d >= 0; --d) {
        if (tid < 256) hist[tid] = 0;
        __syncthreads();
        int shl = 8 * d;
        int last = -1; uint32_t run = 0;
#pragma unroll
        for (int it = 0; it < 6; ++it) {
            if (tid + it * 1024 < NQUAD) {
                uint32_t vals[4] = {sv[it].x, sv[it].y, sv[it].z, sv[it].w};
#pragma unroll
                for (int u = 0; u < 4; ++u) {
                    uint32_t sb = vals[u];
                    bool m = (d == 3) || ((sb >> (shl + 8)) == prefix);
                    int dig = m ? (int)((sb >> shl) & 255u) : -1;
                    if (dig != last) {
                        if (last >= 0 && run) atomicAdd(&hist[last], run);
                        last = dig; run = 0;
                    }
                    if (dig >= 0) run++;
                }
            }
        }
        if (last >= 0 && run) atomicAdd(&hist[last], run);
        __syncthreads();

        // wave 0: suffix-sum over 256 bins (4 bins/lane) + threshold pick
        if (tid < 64) {
            uint4 h4 = *(const uint4*)&hist[tid * 4];
            uint32_t s3 = h4.w;
            uint32_t s2 = h4.z + s3;
            uint32_t s1 = h4.y + s2;
            uint32_t s0 = h4.x + s1;          // sum of this lane's 4 bins..end of lane
            uint32_t acc = s0;                 // inclusive suffix over lanes
#pragma unroll
            for (int off = 1; off < 64; off <<= 1) {
                uint32_t t = __shfl_down(acc, off, 64);
                if (tid + off < 64) acc += t;
            }
            uint32_t above = acc - s0;         // sum over bins >= 4*(lane+1)
            uint32_t cge [4] = {above + s0, above + s1, above + s2, above + s3};
            uint32_t cge1[4] = {above + s1, above + s2, above + s3, above};
#pragma unroll
            for (int u = 0; u < 4; ++u) {
                if (cge[u] >= (uint32_t)R && cge1[u] < (uint32_t)R) {
                    prefix_sh = (prefix << 8) | (uint32_t)(tid * 4 + u);
                    R_sh = R - (int)cge1[u];
                }
            }
        }
        __syncthreads();
        prefix = prefix_sh;
        R = R_sh;
    }
    uint32_t Sstar = prefix;

    // ---- candidate collection (from registers) ----
#pragma unroll
    for (int it = 0; it < 6; ++it) {
        if (tid + it * 1024 < NQUAD) {
            uint32_t vals[4] = {sv[it].x, sv[it].y, sv[it].z, sv[it].w};
#pragma unroll
            for (int u = 0; u < 4; ++u) {
                uint32_t sb = vals[u];
                if (sb >= Sstar) {
                    uint32_t n = (uint32_t)((tid + it * 1024) * 4 + u);
                    uint32_t slot = atomicAdd(&cnt_sh, 1u);
                    if (slot < 2048)
                        keys[slot] = ((uint64_t)sb << 32) | (uint32_t)(~n);
                }
            }
        }
    }
    __syncthreads();
    uint32_t cnt = cnt_sh > 2048u ? 2048u : cnt_sh;
    if (tid < 8) keys[cnt + tid] = 0;          // zero-pad for 8-unrolled scan
    __syncthreads();

    // ---- rank + gather ----
    float lmax = -3.0e38f;
    float4 v0, v1; int cl0 = 0, cl1 = 0; bool k0 = false, k1 = false;
    int rk0 = 0, rk1 = 0;
    uint64_t myk0 = 0, myk1 = 0;

    if (tid < (int)cnt) {
        myk0 = keys[tid];
        for (int j = 0; j < (int)cnt; j += 8) {
            uint64_t a0 = keys[j + 0], a1 = keys[j + 1], a2 = keys[j + 2], a3 = keys[j + 3];
            uint64_t a4 = keys[j + 4], a5 = keys[j + 5], a6 = keys[j + 6], a7 = keys[j + 7];
            rk0 += (int)(a0 > myk0) + (int)(a1 > myk0) + (int)(a2 > myk0) + (int)(a3 > myk0)
                 + (int)(a4 > myk0) + (int)(a5 > myk0) + (int)(a6 > myk0) + (int)(a7 > myk0);
        }
        if (rk0 < MAXDET) {
            uint32_t n = ~(uint32_t)myk0;
            v0 = boxes[(size_t)b * NLOC + n];
            cl0 = cls_ws[(size_t)b * NLOC + n];
            topk_score[b * MAXDET + rk0] = __uint_as_float((uint32_t)(myk0 >> 32));
            gbox[b * MAXDET + rk0] = v0;
            gcls[b * MAXDET + rk0] = cl0;
            lmax = fmaxf(fmaxf(v0.x, v0.y), fmaxf(v0.z, v0.w));
            k0 = true;
        }
    }
    if ((int)cnt > 1024 && tid + 1024 < (int)cnt) {   // rare tie-overflow path
        myk1 = keys[tid + 1024];
        for (int j = 0; j < (int)cnt; j += 8) {
            uint64_t a0 = keys[j + 0], a1 = keys[j + 1], a2 = keys[j + 2], a3 = keys[j + 3];
            uint64_t a4 = keys[j + 4], a5 = keys[j + 5], a6 = keys[j + 6], a7 = keys[j + 7];
            rk1 += (int)(a0 > myk1) + (int)(a1 > myk1) + (int)(a2 > myk1) + (int)(a3 > myk1)
                 + (int)(a4 > myk1) + (int)(a5 > myk1) + (int)(a6 > myk1) + (int)(a7 > myk1);
        }
        if (rk1 < MAXDET) {
            uint32_t n = ~(uint32_t)myk1;
            v1 = boxes[(size_t)b * NLOC + n];
            cl1 = cls_ws[(size_t)b * NLOC + n];
            topk_score[b * MAXDET + rk1] = __uint_as_float((uint32_t)(myk1 >> 32));
            gbox[b * MAXDET + rk1] = v1;
            gcls[b * MAXDET + rk1] = cl1;
            lmax = fmaxf(lmax, fmaxf(fmaxf(v1.x, v1.y), fmaxf(v1.z, v1.w)));
            k1 = true;
        }
    }

#pragma unroll
    for (int off = 32; off > 0; off >>= 1)
        lmax = fmaxf(lmax, __shfl_down(lmax, off, 64));
    if ((tid & 63) == 0) redmax[tid >> 6] = lmax;
    __syncthreads();
    if (tid == 0) {
        float m = redmax[0];
        for (int w = 1; w < 16; ++w) m = fmaxf(m, redmax[w]);
        maxc_sh = __fadd_rn(m, 1.0f);
    }
    __syncthreads();
    float maxc1 = maxc_sh;

    if (k0) {
        float off0 = __fmul_rn((float)cl0, maxc1);
        float4 o = make_float4(__fadd_rn(v0.x, off0), __fadd_rn(v0.y, off0),
                               __fadd_rn(v0.z, off0), __fadd_rn(v0.w, off0));
        obox[b * MAXDET + rk0] = o;
        areas[b * MAXDET + rk0] =
            __fmul_rn(__fadd_rn(__fsub_rn(o.z, o.x), 1.0f),
                      __fadd_rn(__fsub_rn(o.w, o.y), 1.0f));
    }
    if (k1) {
        float off1 = __fmul_rn((float)cl1, maxc1);
        float4 o = make_float4(__fadd_rn(v1.x, off1), __fadd_rn(v1.y, off1),
                               __fadd_rn(v1.z, off1), __fadd_rn(v1.w, off1));
        obox[b * MAXDET + rk1] = o;
        areas[b * MAXDET + rk1] =
            __fmul_rn(__fadd_rn(__fsub_rn(o.z, o.x), 1.0f),
                      __fadd_rn(__fsub_rn(o.w, o.y), 1.0f));
    }
}

// ---------------------------------------------------------------------------
// K4: suppression bits per (row i, 64-col word) + nonzero-row bitmap.
// [unchanged — verified]
// ---------------------------------------------------------------------------
__global__ __launch_bounds__(256) void k_iou(const float4* obox, const float* areas,
                                             uint64_t* rows, uint64_t* nzmask) {
    __shared__ float4 ob[MAXDET];
    __shared__ float  ca[MAXDET];
    __shared__ uint64_t nzloc[16];
    int b = blockIdx.x, word = blockIdx.y, tid = threadIdx.x;
    if (tid < 16) nzloc[tid] = 0;
    for (int r = tid; r < MAXDET; r += 256) {
        ob[r] = obox[b * MAXDET + r];
        ca[r] = areas[b * MAXDET + r];
    }
    __syncthreads();

    int j0 = word * 64;
    int jlim = MAXDET - j0;
    if (jlim > 64) jlim = 64;

#pragma unroll
    for (int qr = 0; qr < 4; ++qr) {
        int i = tid + qr * 256;
        if (i >= MAXDET) continue;
        uint64_t rw = 0;
        int jmax = j0 + jlim;
        if (i < jmax - 1) {
            float4 bi = ob[i];
            float ai = ca[i];
            for (int jj = 0; jj < jlim; ++jj) {
                int j = j0 + jj;
                float4 bj = ob[j0 + jj];
                float xx1 = fmaxf(bi.x, bj.x), yy1 = fmaxf(bi.y, bj.y);
                float xx2 = fminf(bi.z, bj.z), yy2 = fminf(bi.w, bj.w);
                float w_ = fmaxf(__fsub_rn(xx2, xx1), 0.0f);
                float h_ = fmaxf(__fsub_rn(yy2, yy1), 0.0f);
                float inter = __fmul_rn(w_, h_);
                float denom = __fsub_rn(__fadd_rn(ai, ca[j0 + jj]), inter);
                bool sup = (j > i) && (inter > __fmul_rn(0.6f, denom));
                rw |= sup ? (1ull << jj) : 0ull;
            }
        }
        rows[((size_t)(b * MAXDET) + i) * 16 + word] = rw;
        if (rw) atomicOr(&nzloc[i >> 6], 1ull << (i & 63));
    }
    __syncthreads();
    if (tid < 16 && nzloc[tid])
        atomicOr(&nzmask[b * 16 + tid], nzloc[tid]);
}

// ---------------------------------------------------------------------------
// K5: sparse greedy scan.  NEW: all nonzero rows bulk-staged into LDS by the
// whole block BEFORE the serial recurrence, so the serial chain reads LDS
// instead of paying a cross-XCD HBM round-trip per iteration.  Global
// prefetch-1-ahead fallback for (rare) m > NZSTG.
// ---------------------------------------------------------------------------
#define NZSTG 448   // staged rows: 448*16*8 = 57344 B LDS

__global__ __launch_bounds__(256) void k_nms_out(const uint64_t* rows,
                                                 const uint64_t* nzmask,
                                                 const float* topk_score,
                                                 const int* gcls, const float4* gbox,
                                                 float* out) {
    __shared__ uint64_t validmask[16];
    __shared__ uint64_t keepmask[16];
    __shared__ int zlist[MAXDET];
    __shared__ int m_sh;
    __shared__ uint64_t srow[NZSTG * 16];
    int b = blockIdx.x, tid = threadIdx.x;

    if (tid < 16) validmask[tid] = 0;
    if (tid == 0) m_sh = 0;
    __syncthreads();
    for (int r = tid; r < MAXDET; r += 256)
        if (topk_score[b * MAXDET + r] >= 0.05f)
            atomicOr(&validmask[r >> 6], 1ull << (r & 63));
    if (tid == 0) {                          // ascending z-list of nonzero rows
        int m = 0;
        for (int w = 0; w < 16; ++w) {
            uint64_t nz = nzmask[b * 16 + w];
            while (nz) {
                int bit = __ffsll((unsigned long long)nz) - 1;
                nz &= nz - 1;
                zlist[m++] = w * 64 + bit;
            }
        }
        m_sh = m;
    }
    __syncthreads();

    int m = m_sh;
    int ms = m < NZSTG ? m : NZSTG;
    const uint64_t* rg = rows + (size_t)b * MAXDET * 16;

    // bulk-stage nonzero rows (coalesced 128 B per row)
    for (int idx = tid; idx < ms * 16; idx += 256)
        srow[idx] = rg[(size_t)zlist[idx >> 4] * 16 + (idx & 15)];
    __syncthreads();

    uint64_t S = 0, V = 0;
    if (tid < 16) V = validmask[tid];
    if (tid < 64) {                          // wave 0 only
        uint64_t row_nxt = 0;
        if (m > 0 && tid < 16)
            row_nxt = (0 < ms) ? srow[tid] : rg[(size_t)zlist[0] * 16 + tid];
        for (int k = 0; k < m; ++k) {
            uint64_t row_cur = row_nxt;
            int kn = k + 1;
            if (kn < m && tid < 16)
                row_nxt = (kn < ms) ? srow[kn * 16 + tid]
                                    : rg[(size_t)zlist[kn] * 16 + tid];
            int z = zlist[k];
            int w = z >> 6, bp = z & 63;
            uint32_t aliveV = ((uint32_t)(V >> bp) & ~(uint32_t)(S >> bp)) & 1u;
            uint32_t alive = (uint32_t)__builtin_amdgcn_readlane((int)aliveV, w);
            if (alive) S |= row_cur;
        }
    }
    if (tid < 16) keepmask[tid] = V & ~S;
    __syncthreads();

    for (int r = tid; r < MAXDET; r += 256) {
        bool keep = ((keepmask[r >> 6] >> (r & 63)) & 1ull) != 0;
        float sc = topk_score[b * MAXDET + r];
        int cl = gcls[b * MAXDET + r];
        float4 v = gbox[b * MAXDET + r];
        float c0 = fminf(fmaxf(v.x, 0.0f), 1023.0f);
        float c1 = fminf(fmaxf(v.y, 0.0f), 1023.0f);
        float c2 = fminf(fmaxf(v.z, 0.0f), 1023.0f);
        float c3 = fminf(fmaxf(v.w, 0.0f), 1023.0f);
        out[b * MAXDET + r] = keep ? sc : 0.0f;
        out[BATCH * MAXDET + b * MAXDET + r] = keep ? (float)cl : 0.0f;
        float4* op = (float4*)(out + 2 * BATCH * MAXDET) + (b * MAXDET + r);
        *op = keep ? make_float4(c0, c1, c2, c3) : make_float4(0.f, 0.f, 0.f, 0.f);
    }
}

// ---------------------------------------------------------------------------
extern "C" void kernel_launch(void* const* d_in, const int* in_sizes, int n_in,
                              void* d_out, int out_size, void* d_ws, size_t ws_size,
                              hipStream_t stream) {
    (void)in_sizes; (void)n_in; (void)out_size; (void)ws_size;

    LevelPtrs lp;
    for (int i = 0; i < 5; ++i) {
        lp.cls[i] = (const float*)d_in[3 * i + 0];
        lp.cnt[i] = (const float*)d_in[3 * i + 1];
        lp.reg[i] = (const float*)d_in[3 * i + 2];
    }

    char* ws = (char*)d_ws;
    float*    scores   = (float*)   (ws + 0);          // 8*21824*4   = 698368
    int*      cls_ws   = (int*)     (ws + 698368);     // 698368
    float4*   boxes    = (float4*)  (ws + 1396736);    // 8*21824*16  = 2793472
    float*    topk_sc  = (float*)   (ws + 4222208);    // 32000
    int*      gcls     = (int*)     (ws + 4254208);    // 32000
    float4*   gbox     = (float4*)  (ws + 4286208);    // 128000
    float4*   obox     = (float4*)  (ws + 4414208);    // 128000
    float*    areas    = (float*)   (ws + 4542208);    // 32000
    uint64_t* rows     = (uint64_t*)(ws + 4574208);    // 8*1000*16*8 = 1024000
    uint64_t* nzmask   = (uint64_t*)(ws + 5598208);    // 8*16*8      = 1024

    dim3 g1(171, BATCH);
    k_stage1<<<g1, 256, 0, stream>>>(lp, scores, cls_ws, boxes);

    k_select<<<BATCH, 1024, 0, stream>>>((const uint32_t*)scores, boxes, cls_ws,
                                         topk_sc, gbox, gcls, obox, areas, nzmask);

    dim3 g4(BATCH, 16);
    k_iou<<<g4, 256, 0, stream>>>(obox, areas, rows, nzmask);

    k_nms_out<<<BATCH, 256, 0, stream>>>(rows, nzmask, topk_sc, gcls, gbox,
                                         (float*)d_out);
}